// Round 10
// baseline (290.031 us; speedup 1.0000x reference)
//
#include <hip/hip_runtime.h>
#include <hip/hip_bf16.h>

// GAT 2-layer inference, round 10:
//  - REVERT round 9's inline-sort gathers: 391 blocks x 16 waves underfilled the
//    machine (occupancy 43%, 2.7 TB/s vs 3.9) and paid the sort twice. g1/g2 are
//    back to wave-per-dst 256-thr blocks (measured 3.9 TB/s); binB reinstated (one sort).
//  - KEEP: fused1 (gemm1 MFMA + binA overlapped), bf16 agg1, bf16 h1/h2, MFMA gemm2.
//  - zero_kernel replaced by hipMemsetAsync(bincur,0) + rbase = b*CAP + atomic.
// N=100000, E=1600000 (+N self loops), IN_C=128, L1: 4 heads x 32, L2: 1 head x 32.
// Softmax as fused weighted mean, no max-subtraction (validated rounds 1-9).
// g1 sits on a past-L2 random-gather plateau (~235 MB @ ~3.9 TB/s) — rounds 6/7
// proved ILP/VALU restructuring neutral there.

#define NSLOPE 0.2f
#define GSTRIDE 136    // bf16 LDS row stride for MFMA tiles (68 words == 4 mod 32)
#define NB_MAX 400     // bins = ceil(N/256) = 391 for N=100k
#define CHUNK 4096     // edges per block in binA role (16 per thread)
#define CAP 5632       // per-bin capacity (mean 4352, sigma 66 -> ~19 sigma margin)

typedef __attribute__((ext_vector_type(8))) short short8;
typedef __attribute__((ext_vector_type(4))) float floatx4;

__device__ __forceinline__ float leaky(float v) { return v > 0.f ? v : NSLOPE * v; }

__device__ __forceinline__ unsigned short f2bf(float f) {
  __hip_bfloat16 b = __float2bfloat16(f);
  return *reinterpret_cast<unsigned short*>(&b);
}
__device__ __forceinline__ float bf2f(unsigned int u) {  // low 16 bits hold bf16
  return __uint_as_float(u << 16);
}
__device__ __forceinline__ unsigned int pack2(float a, float b) {
  return (unsigned int)f2bf(a) | ((unsigned int)f2bf(b) << 16);
}

// ---------------- fused1: gemm1 (blocks < g1blocks) + binA (rest) ----------------
__global__ __launch_bounds__(256, 2) void fused1_kernel(
    const float* __restrict__ x, const float* __restrict__ W,
    const float* __restrict__ atts, const float* __restrict__ attd,
    unsigned short* __restrict__ h, float* __restrict__ asrc, float* __restrict__ adst,
    int n, int g1blocks,
    const int* __restrict__ ei, int* __restrict__ bincur,
    unsigned int* __restrict__ staging, int E, int ET, int nb) {
  __shared__ __align__(16) unsigned char smem[70656];
  const int tid = threadIdx.x;

  if (blockIdx.x < g1blocks) {
    // ---------- gemm1 role: h1 = bf16(x @ W1), asrc1/adst1 dots ----------
    unsigned short* xs = (unsigned short*)smem;            // 128*GSTRIDE shorts
    unsigned short* wt = (unsigned short*)(smem + 34816);  // 128*GSTRIDE shorts
    float* att_s = (float*)(smem + 69632);                 // 128 f
    float* att_d = (float*)(smem + 70144);                 // 128 f
    const int row0 = blockIdx.x * 128;

    if (tid < 128) { att_s[tid] = atts[tid]; att_d[tid] = attd[tid]; }

    const float4* w4 = (const float4*)W;
#pragma unroll
    for (int i = 0; i < 16; i++) {
      int idx = tid + i * 256;         // 4096 float4s
      int k = idx >> 5, n0 = (idx & 31) * 4;
      float4 v = w4[idx];
      float vv[4] = {v.x, v.y, v.z, v.w};
#pragma unroll
      for (int jj = 0; jj < 4; jj++) {
        int j = (jj + tid) & 3;
        wt[(n0 + j) * GSTRIDE + k] = f2bf(vv[j]);
      }
    }

    const float4* x4 = (const float4*)x;
#pragma unroll
    for (int i = 0; i < 16; i++) {
      int idx = tid + i * 256;
      int r = idx >> 5, c4 = idx & 31;
      float4 v = make_float4(0.f, 0.f, 0.f, 0.f);
      if (row0 + r < n) v = x4[(size_t)(row0 + r) * 32 + c4];
      unsigned int* p = (unsigned int*)&xs[r * GSTRIDE + c4 * 4];
      p[0] = pack2(v.x, v.y);
      p[1] = pack2(v.z, v.w);
    }
    __syncthreads();

    const int l = tid & 63;
    const int w = tid >> 6;
    const int mrow = l & 15;
    const int q = l >> 4;
    floatx4 acc[2][8];
#pragma unroll
    for (int mt = 0; mt < 2; mt++)
#pragma unroll
      for (int nt = 0; nt < 8; nt++) acc[mt][nt] = (floatx4){0.f, 0.f, 0.f, 0.f};

#pragma unroll
    for (int ks = 0; ks < 4; ks++) {
      const int k0 = ks * 32 + q * 8;
      short8 a0 = *(const short8*)&xs[(w * 32 + mrow) * GSTRIDE + k0];
      short8 a1 = *(const short8*)&xs[(w * 32 + 16 + mrow) * GSTRIDE + k0];
#pragma unroll
      for (int nt = 0; nt < 8; nt++) {
        short8 b = *(const short8*)&wt[(nt * 16 + mrow) * GSTRIDE + k0];
        acc[0][nt] = __builtin_amdgcn_mfma_f32_16x16x32_bf16(a0, b, acc[0][nt], 0, 0, 0);
        acc[1][nt] = __builtin_amdgcn_mfma_f32_16x16x32_bf16(a1, b, acc[1][nt], 0, 0, 0);
      }
    }
    __syncthreads();

#pragma unroll
    for (int mt = 0; mt < 2; mt++)
#pragma unroll
      for (int nt = 0; nt < 8; nt++)
#pragma unroll
        for (int i = 0; i < 4; i++) {
          int r = w * 32 + mt * 16 + q * 4 + i;
          xs[r * GSTRIDE + nt * 16 + mrow] = f2bf(acc[mt][nt][i]);
        }
    __syncthreads();

#pragma unroll
    for (int i = 0; i < 8; i++) {
      int idx = tid + i * 256;        // 2048
      int r = idx >> 4, c8 = (idx & 15) * 8;
      if (row0 + r < n) {
        unsigned int* p = (unsigned int*)&xs[r * GSTRIDE + c8];
        uint4 v = make_uint4(p[0], p[1], p[2], p[3]);
        *(uint4*)(h + (size_t)(row0 + r) * 128 + c8) = v;
      }
    }

#pragma unroll
    for (int rr = 0; rr < 2; rr++) {
      int row = (tid >> 2) + rr * 64;
      int head = tid & 3;
      float ss = 0.f, sd = 0.f;
#pragma unroll
      for (int c = 0; c < 32; c++) {
        int cr = (c + tid) & 31;
        float hv = bf2f(xs[row * GSTRIDE + head * 32 + cr]);
        ss += hv * att_s[head * 32 + cr];
        sd += hv * att_d[head * 32 + cr];
      }
      if (row0 + row < n) {
        asrc[(size_t)(row0 + row) * 4 + head] = ss;
        adst[(size_t)(row0 + row) * 4 + head] = sd;
      }
    }
  } else {
    // ---------- binA role: scatter packed (src, dst&255) into fixed-stride bins ----------
    int* hist  = (int*)smem;           // NB_MAX
    int* run   = (int*)(smem + 1600);  // NB_MAX
    int* rbase = (int*)(smem + 3200);  // NB_MAX
    const int base = (blockIdx.x - g1blocks) * CHUNK;
    for (int i = tid; i < nb; i += 256) { hist[i] = 0; run[i] = 0; }
    __syncthreads();
    int se[16], de[16];
#pragma unroll
    for (int j = 0; j < 16; j++) {
      int idx = base + j * 256 + tid;
      if (idx < ET) {
        if (idx < E) { se[j] = ei[idx]; de[j] = ei[E + idx]; }
        else         { se[j] = de[j] = idx - E; }
        atomicAdd(&hist[de[j] >> 8], 1);
      } else de[j] = -1;
    }
    __syncthreads();
    for (int i = tid; i < nb; i += 256)
      rbase[i] = hist[i] ? (i * CAP + atomicAdd(&bincur[i], hist[i])) : 0;
    __syncthreads();
#pragma unroll
    for (int j = 0; j < 16; j++) {
      if (de[j] >= 0) {
        int b = de[j] >> 8;
        int ofs = atomicAdd(&run[b], 1);
        staging[(size_t)rbase[b] + ofs] =
            (unsigned)se[j] | ((unsigned)(de[j] & 255) << 17);
      }
    }
  }
}

// ---------------- binB: per bin -> rowbeg/rowend + bucket placement (fixed-stride space) ----------------
__global__ __launch_bounds__(256) void binB_kernel(const unsigned int* __restrict__ staging,
                                                   const int* __restrict__ bincur,
                                                   int* __restrict__ rowbeg,
                                                   int* __restrict__ rowend,
                                                   int* __restrict__ bucket, int n) {
  __shared__ int cnt[256];
  __shared__ int cur[256];
  const int b = blockIdx.x;
  const int t = threadIdx.x;
  const int d0 = b << 8;
  const int nd = min(256, n - d0);
  const int base = b * CAP;
  const int rcnt = bincur[b];
  cnt[t] = 0;
  __syncthreads();
  for (int j = t; j < rcnt; j += 256) {
    unsigned int r = staging[(size_t)base + j];
    atomicAdd(&cnt[r >> 17], 1);
  }
  __syncthreads();
  int v = cnt[t];
  cur[t] = v;
  __syncthreads();
  for (int off = 1; off < 256; off <<= 1) {
    int add = (t >= off) ? cur[t - off] : 0;
    __syncthreads();
    cur[t] += add;
    __syncthreads();
  }
  int start = base + cur[t] - v;  // exclusive prefix within bin
  if (t < nd) { rowbeg[d0 + t] = start; rowend[d0 + t] = start + v; }
  __syncthreads();
  cur[t] = start;
  __syncthreads();
  for (int j = t; j < rcnt; j += 256) {
    unsigned int r = staging[(size_t)base + j];
    int pos = atomicAdd(&cur[r >> 17], 1);
    bucket[pos] = (int)(r & 0x1FFFFu);
  }
}

// ---------------- g1: wave per dst, 8 edges/iter (8-lane groups); bf16 agg out ----------------
__global__ __launch_bounds__(256) void g1_kernel(const int* __restrict__ rowbeg,
                                                 const int* __restrict__ rowend,
                                                 const int* __restrict__ bucket,
                                                 const float* __restrict__ asrc,
                                                 const float* __restrict__ adst,
                                                 const unsigned int* __restrict__ h,  // bf16x2, row stride 64
                                                 unsigned short* __restrict__ agg,    // bf16 out
                                                 int n) {
  const int lane = threadIdx.x & 63;
  const int g = lane >> 3;
  const int l8 = lane & 7;
  const int head = l8 >> 1;
  const int d = blockIdx.x * 4 + (threadIdx.x >> 6);
  if (d >= n) return;
  const float ad = adst[(size_t)d * 4 + head];
  const int beg = rowbeg[d], end = rowend[d];
  float num[16];
#pragma unroll
  for (int j = 0; j < 16; j++) num[j] = 0.f;
  float den = 0.f;

  int i = beg + g;
  if (i < end) {
    int s = bucket[i];
    for (;;) {
      float a = asrc[(size_t)s * 4 + head];
      const uint4* hp = (const uint4*)(h + (size_t)s * 64 + l8 * 8);
      uint4 h0 = hp[0];
      uint4 h1v = hp[1];
      int i2 = i + 8;
      int s2 = (i2 < end) ? bucket[i2] : 0;
      float w = __expf(leaky(a + ad));
      den += w;
      num[0]  += w * bf2f(h0.x & 0xffffu);  num[1]  += w * bf2f(h0.x >> 16);
      num[2]  += w * bf2f(h0.y & 0xffffu);  num[3]  += w * bf2f(h0.y >> 16);
      num[4]  += w * bf2f(h0.z & 0xffffu);  num[5]  += w * bf2f(h0.z >> 16);
      num[6]  += w * bf2f(h0.w & 0xffffu);  num[7]  += w * bf2f(h0.w >> 16);
      num[8]  += w * bf2f(h1v.x & 0xffffu); num[9]  += w * bf2f(h1v.x >> 16);
      num[10] += w * bf2f(h1v.y & 0xffffu); num[11] += w * bf2f(h1v.y >> 16);
      num[12] += w * bf2f(h1v.z & 0xffffu); num[13] += w * bf2f(h1v.z >> 16);
      num[14] += w * bf2f(h1v.w & 0xffffu); num[15] += w * bf2f(h1v.w >> 16);
      if (i2 >= end) break;
      i = i2; s = s2;
    }
  }
#pragma unroll
  for (int j = 0; j < 16; j++) {
    num[j] += __shfl_xor(num[j], 8, 64);
    num[j] += __shfl_xor(num[j], 16, 64);
    num[j] += __shfl_xor(num[j], 32, 64);
  }
  den += __shfl_xor(den, 8, 64);
  den += __shfl_xor(den, 16, 64);
  den += __shfl_xor(den, 32, 64);
  if (g == 0) {
    float inv = 1.f / (den + 1e-16f);
    unsigned short* p = agg + (size_t)d * 128 + l8 * 16;
    uint4 o0, o1;
    o0.x = pack2(num[0] * inv, num[1] * inv);
    o0.y = pack2(num[2] * inv, num[3] * inv);
    o0.z = pack2(num[4] * inv, num[5] * inv);
    o0.w = pack2(num[6] * inv, num[7] * inv);
    o1.x = pack2(num[8] * inv, num[9] * inv);
    o1.y = pack2(num[10] * inv, num[11] * inv);
    o1.z = pack2(num[12] * inv, num[13] * inv);
    o1.w = pack2(num[14] * inv, num[15] * inv);
    *(uint4*)p = o0;
    *(uint4*)(p + 8) = o1;
  }
}

// ---------------- GEMM2 (bf16 MFMA): x2 = relu(agg1+b1); h2 = x2 @ W2 ; a2 dots ----------------
__global__ __launch_bounds__(256, 2) void gemm2_kernel(const unsigned short* __restrict__ agg1,  // bf16
                                                       const float* __restrict__ b1,
                                                       const float* __restrict__ W,
                                                       const float* __restrict__ atts,
                                                       const float* __restrict__ attd,
                                                       unsigned short* __restrict__ h2,
                                                       float* __restrict__ asrc,
                                                       float* __restrict__ adst, int n) {
  __shared__ __align__(16) unsigned short xs[128 * GSTRIDE];  // x2 tile bf16
  __shared__ __align__(16) unsigned short wt[32 * GSTRIDE];   // W2^T bf16: wt[n][k]
  __shared__ __align__(16) unsigned short hs[128 * 36];       // h2 tile bf16
  __shared__ float att_s[32], att_d[32];
  const int tid = threadIdx.x;
  const int row0 = blockIdx.x * 128;

  if (tid < 32) { att_s[tid] = atts[tid]; att_d[tid] = attd[tid]; }

  const float4* w4 = (const float4*)W;
#pragma unroll
  for (int i = 0; i < 4; i++) {
    int idx = tid + i * 256;
    int k = idx >> 3, n0 = (idx & 7) * 4;
    float4 v = w4[idx];
    float vv[4] = {v.x, v.y, v.z, v.w};
#pragma unroll
    for (int jj = 0; jj < 4; jj++) {
      int j = (jj + tid) & 3;
      wt[(n0 + j) * GSTRIDE + k] = f2bf(vv[j]);
    }
  }

  // stage x2 = relu(bf16 agg1 + b1); agg1 row = 16 uint4 -> 2048 loads
  const uint4* a4 = (const uint4*)agg1;
#pragma unroll
  for (int i = 0; i < 8; i++) {
    int idx = tid + i * 256;        // 2048
    int r = idx >> 4, c8 = (idx & 15) * 8;
    uint4 v = make_uint4(0, 0, 0, 0);
    if (row0 + r < n) v = a4[(size_t)(row0 + r) * 16 + (idx & 15)];
    unsigned int* p = (unsigned int*)&xs[r * GSTRIDE + c8];
    unsigned int vw[4] = {v.x, v.y, v.z, v.w};
#pragma unroll
    for (int j = 0; j < 4; j++) {
      float lo = fmaxf(bf2f(vw[j] & 0xffffu) + b1[c8 + j * 2], 0.f);
      float hi = fmaxf(bf2f(vw[j] >> 16) + b1[c8 + j * 2 + 1], 0.f);
      p[j] = pack2(lo, hi);
    }
  }
  __syncthreads();

  const int l = tid & 63;
  const int w = tid >> 6;
  const int mrow = l & 15;
  const int q = l >> 4;
  floatx4 acc[2][2];
#pragma unroll
  for (int mt = 0; mt < 2; mt++)
#pragma unroll
    for (int nt = 0; nt < 2; nt++) acc[mt][nt] = (floatx4){0.f, 0.f, 0.f, 0.f};

#pragma unroll
  for (int ks = 0; ks < 4; ks++) {
    const int k0 = ks * 32 + q * 8;
    short8 a0 = *(const short8*)&xs[(w * 32 + mrow) * GSTRIDE + k0];
    short8 a1 = *(const short8*)&xs[(w * 32 + 16 + mrow) * GSTRIDE + k0];
#pragma unroll
    for (int nt = 0; nt < 2; nt++) {
      short8 b = *(const short8*)&wt[(nt * 16 + mrow) * GSTRIDE + k0];
      acc[0][nt] = __builtin_amdgcn_mfma_f32_16x16x32_bf16(a0, b, acc[0][nt], 0, 0, 0);
      acc[1][nt] = __builtin_amdgcn_mfma_f32_16x16x32_bf16(a1, b, acc[1][nt], 0, 0, 0);
    }
  }

#pragma unroll
  for (int mt = 0; mt < 2; mt++)
#pragma unroll
    for (int nt = 0; nt < 2; nt++)
#pragma unroll
      for (int i = 0; i < 4; i++) {
        int r = w * 32 + mt * 16 + q * 4 + i;
        hs[r * 36 + nt * 16 + mrow] = f2bf(acc[mt][nt][i]);
      }
  __syncthreads();

#pragma unroll
  for (int i = 0; i < 4; i++) {
    int idx = tid + i * 256;        // 1024
    int r = idx >> 3, c4 = (idx & 7) * 4;
    if (row0 + r < n) {
      unsigned int* p = (unsigned int*)&hs[r * 36 + c4];
      *(uint2*)(h2 + (size_t)(row0 + r) * 32 + c4) = make_uint2(p[0], p[1]);
    }
  }

  if (tid < 128) {
    int row = tid;
    float ss = 0.f, sd = 0.f;
#pragma unroll
    for (int c = 0; c < 32; c++) {
      int cr = (c + tid) & 31;
      float hv = bf2f(hs[row * 36 + cr]);
      ss += hv * att_s[cr];
      sd += hv * att_d[cr];
    }
    if (row0 + row < n) { asrc[row0 + row] = ss; adst[row0 + row] = sd; }
  }
}

// ---------------- g2: wave per dst, 8 edges/iter (8-lane groups) ----------------
__global__ __launch_bounds__(256) void g2_kernel(const int* __restrict__ rowbeg,
                                                 const int* __restrict__ rowend,
                                                 const int* __restrict__ bucket,
                                                 const float* __restrict__ asrc,
                                                 const float* __restrict__ adst,
                                                 const unsigned int* __restrict__ h2,  // bf16x2, row stride 16
                                                 const float* __restrict__ b2,
                                                 float* __restrict__ out, int n) {
  const int lane = threadIdx.x & 63;
  const int g = lane >> 3;
  const int l8 = lane & 7;
  const int d = blockIdx.x * 4 + (threadIdx.x >> 6);
  if (d >= n) return;
  const float ad = adst[d];
  const int beg = rowbeg[d], end = rowend[d];
  float num[4];
#pragma unroll
  for (int j = 0; j < 4; j++) num[j] = 0.f;
  float den = 0.f;

  int i = beg + g;
  if (i < end) {
    int s = bucket[i];
    for (;;) {
      float a = asrc[s];
      uint2 hv = *(const uint2*)(h2 + (size_t)s * 16 + l8 * 2);
      int i2 = i + 8;
      int s2 = (i2 < end) ? bucket[i2] : 0;
      float w = __expf(leaky(a + ad));
      den += w;
      num[0] += w * bf2f(hv.x & 0xffffu); num[1] += w * bf2f(hv.x >> 16);
      num[2] += w * bf2f(hv.y & 0xffffu); num[3] += w * bf2f(hv.y >> 16);
      if (i2 >= end) break;
      i = i2; s = s2;
    }
  }
#pragma unroll
  for (int j = 0; j < 4; j++) {
    num[j] += __shfl_xor(num[j], 8, 64);
    num[j] += __shfl_xor(num[j], 16, 64);
    num[j] += __shfl_xor(num[j], 32, 64);
  }
  den += __shfl_xor(den, 8, 64);
  den += __shfl_xor(den, 16, 64);
  den += __shfl_xor(den, 32, 64);
  if (g == 0) {
    float inv = 1.f / (den + 1e-16f);
    float4 bb = ((const float4*)b2)[l8];  // b2: 32 floats = 8 float4; l8 in [0,8)
    *(float4*)(out + (size_t)d * 32 + l8 * 4) =
        make_float4(num[0] * inv + bb.x, num[1] * inv + bb.y,
                    num[2] * inv + bb.z, num[3] * inv + bb.w);
  }
}

extern "C" void kernel_launch(void* const* d_in, const int* in_sizes, int n_in,
                              void* d_out, int out_size, void* d_ws, size_t ws_size,
                              hipStream_t stream) {
  const float* x = (const float*)d_in[0];
  const int* ei = (const int*)d_in[1];
  const float* W1 = (const float*)d_in[2];
  const float* atts1 = (const float*)d_in[3];
  const float* attd1 = (const float*)d_in[4];
  const float* b1 = (const float*)d_in[5];
  const float* W2 = (const float*)d_in[6];
  const float* atts2 = (const float*)d_in[7];
  const float* attd2 = (const float*)d_in[8];
  const float* b2 = (const float*)d_in[9];
  float* out = (float*)d_out;

  const int N = in_sizes[0] / 128;
  const int E = in_sizes[1] / 2;
  const int ET = E + N;
  const int NB = (N + 255) >> 8;            // 391 bins (256 dsts each)
  const int NCH = (ET + CHUNK - 1) / CHUNK; // 416 binA-role blocks
  const int G1B = (N + 127) / 128;          // 782 gemm1-role blocks

  // workspace (~74 MB):
  float* wsf = (float*)d_ws;
  float* asrc1 = wsf;                                   // 4N f
  float* adst1 = asrc1 + (size_t)N * 4;                 // 4N f
  float* asrc2 = adst1 + (size_t)N * 4;                 // N f
  float* adst2 = asrc2 + (size_t)N;                     // N f
  unsigned short* agg1 = (unsigned short*)(adst2 + (size_t)N);  // 128N bf16
  unsigned short* h1 = agg1 + (size_t)N * 128;          // 128N bf16 (alias h2)
  unsigned short* h2 = h1;
  int* rowbeg = (int*)(h1 + (size_t)N * 128);           // N
  int* rowend = rowbeg + N;                             // N
  int* bucket = rowend + N;                             // NB*CAP (fixed-stride space)
  unsigned int* staging = (unsigned int*)(bucket + (size_t)NB * CAP);  // NB*CAP
  int* bincur = (int*)(staging + (size_t)NB * CAP);     // NB

  hipMemsetAsync(bincur, 0, NB * sizeof(int), stream);
  fused1_kernel<<<G1B + NCH, 256, 0, stream>>>(x, W1, atts1, attd1, h1, asrc1, adst1,
                                               N, G1B, ei, bincur, staging, E, ET, NB);
  binB_kernel<<<NB, 256, 0, stream>>>(staging, bincur, rowbeg, rowend, bucket, N);
  g1_kernel<<<(N + 3) / 4, 256, 0, stream>>>(rowbeg, rowend, bucket, asrc1, adst1,
                                             (const unsigned int*)h1, agg1, N);
  gemm2_kernel<<<(N + 127) / 128, 256, 0, stream>>>(agg1, b1, W2, atts2, attd2,
                                                    h2, asrc2, adst2, N);
  g2_kernel<<<(N + 3) / 4, 256, 0, stream>>>(rowbeg, rowend, bucket, asrc2, adst2,
                                             (const unsigned int*)h2, b2, out, N);
}